// Round 8
// baseline (148.935 us; speedup 1.0000x reference)
//
#include <hip/hip_runtime.h>

#define T_SEQ 1024
#define C_DIM 512
#define H_HEADS 8
#define HDIM 64
#define B_BATCH 4
#define M_ROWS (B_BATCH * T_SEQ)   // 4096

typedef __attribute__((ext_vector_type(8))) short short8;
typedef __attribute__((ext_vector_type(4))) float f32x4;

__device__ __forceinline__ unsigned short f2bf(float f) {
    unsigned u = __builtin_bit_cast(unsigned, f);
    u += 0x7FFFu + ((u >> 16) & 1u);   // round-to-nearest-even
    return (unsigned short)(u >> 16);
}

// async global->LDS, 16B per lane; LDS dest = uniform base + lane*16
__device__ __forceinline__ void gload_lds16(const unsigned short* g, unsigned short* l) {
    __builtin_amdgcn_global_load_lds(
        (const __attribute__((address_space(1))) unsigned int*)(const void*)g,
        (__attribute__((address_space(3))) unsigned int*)(void*)l, 16, 0, 0);
}

// ---------------------------------------------------------------------------
// Kernel 1: one-shot cast of x + 4 weight matrices to bf16 (r4/r5 showed
// fusing this into GEMM staging costs ~196 MB of per-block fp32 re-reads).
// ---------------------------------------------------------------------------
__global__ __launch_bounds__(256) void cast_all(
    const float* __restrict__ x,
    const float* __restrict__ wq, const float* __restrict__ wk,
    const float* __restrict__ wv, const float* __restrict__ wp,
    unsigned short* __restrict__ xb,
    unsigned short* __restrict__ wqb, unsigned short* __restrict__ wkb,
    unsigned short* __restrict__ wvb, unsigned short* __restrict__ wpb)
{
    const long NX = (long)M_ROWS * C_DIM;
    const long NW = (long)C_DIM * C_DIM;
    long i4 = (long)blockIdx.x * blockDim.x + threadIdx.x;
    long base = i4 * 4;
    const float* src; unsigned short* dst; long off;
    if (base < NX) { src = x; dst = xb; off = base; }
    else {
        long r = base - NX;
        int w = (int)(r >> 18);
        off = r & (NW - 1);
        switch (w) {
            case 0:  src = wq; dst = wqb; break;
            case 1:  src = wk; dst = wkb; break;
            case 2:  src = wv; dst = wvb; break;
            default: src = wp; dst = wpb; break;
        }
    }
    float4 v = *(const float4*)(src + off);
    ushort4 o;
    o.x = f2bf(v.x); o.y = f2bf(v.y); o.z = f2bf(v.z); o.w = f2bf(v.w);
    *(ushort4*)(dst + off) = o;
}

// ---------------------------------------------------------------------------
// m97-style GEMM (r3/r6, known-good): O = A(M x 512) @ W^T(512 x 512) + b.
// 128x128 tile, 256 threads. global_load_lds width=16, unpadded LDS with XOR
// chunk swizzle. mode 0: bf16 (B,H,T,HD); mode 1: bf16 (B,H,HD,T) via swapped
// MFMA operands; mode 2: fp32 M x N.
// ---------------------------------------------------------------------------
__device__ __forceinline__ void gemm_body(
    const unsigned short* __restrict__ A,
    const unsigned short* __restrict__ W,
    const float* __restrict__ bias,
    unsigned short* __restrict__ Obf,
    float* __restrict__ Of,
    int mode)
{
    __shared__ __align__(16) unsigned short Atile[128 * 64];
    __shared__ __align__(16) unsigned short Btile[128 * 64];

    const int tid  = threadIdx.x;
    const int w    = tid >> 6;
    const int lane = tid & 63;
    const int quad = lane >> 4;
    const int l16  = lane & 15;
    const int m0   = blockIdx.x * 128;
    const int n0   = blockIdx.y * 128;
    const int wr   = 64 * (w >> 1);
    const int wc   = 64 * (w & 1);

    f32x4 acc[4][4] = {};

    const int lr = lane >> 3;
    const int lc = lane & 7;

    for (int k0 = 0; k0 < 512; k0 += 64) {
        __syncthreads();
        for (int i = 0; i < 4; ++i) {
            int r0 = 32 * w + 8 * i;
            int r  = r0 + lr;
            int c  = lc ^ (r & 7);      // XOR swizzle
            gload_lds16(&A[(long)(m0 + r) * 512 + k0 + c * 8], &Atile[r0 * 64]);
            gload_lds16(&W[(long)(n0 + r) * 512 + k0 + c * 8], &Btile[r0 * 64]);
        }
        __syncthreads();

        for (int st = 0; st < 2; ++st) {
            const int pc = ((4 * st + quad) ^ (l16 & 7)) * 8;
            short8 af[4], bf[4];
            for (int i = 0; i < 4; ++i)
                af[i] = *(const short8*)&Atile[(wr + 16 * i + l16) * 64 + pc];
            for (int j = 0; j < 4; ++j)
                bf[j] = *(const short8*)&Btile[(wc + 16 * j + l16) * 64 + pc];
            for (int i = 0; i < 4; ++i)
                for (int j = 0; j < 4; ++j)
                    acc[i][j] = (mode == 1)
                        ? __builtin_amdgcn_mfma_f32_16x16x32_bf16(bf[j], af[i], acc[i][j], 0, 0, 0)
                        : __builtin_amdgcn_mfma_f32_16x16x32_bf16(af[i], bf[j], acc[i][j], 0, 0, 0);
        }
    }

    if (mode == 1) {
        for (int j = 0; j < 4; ++j) {
            for (int reg = 0; reg < 4; ++reg) {
                int n = n0 + wc + 16 * j + 4 * quad + reg;
                int h = n >> 6, hd = n & 63;
                float bv = bias[n];
                for (int i = 0; i < 4; ++i) {
                    int t = m0 + wr + 16 * i + l16;
                    int b = t >> 10, tl = t & 1023;
                    Obf[(((long)(b * H_HEADS + h)) * HDIM + hd) * T_SEQ + tl] =
                        f2bf(acc[i][j][reg] + bv);
                }
            }
        }
    } else {
        for (int j = 0; j < 4; ++j) {
            int col = n0 + wc + 16 * j + l16;
            float bv = bias[col];
            for (int i = 0; i < 4; ++i) {
                for (int reg = 0; reg < 4; ++reg) {
                    int row = m0 + wr + 16 * i + 4 * quad + reg;
                    float v = acc[i][j][reg] + bv;
                    if (mode == 2) {
                        Of[(long)row * 512 + col] = v;
                    } else {
                        int b = row >> 10, t = row & 1023;
                        int h = col >> 6,  hd = col & 63;
                        Obf[(((long)(b * H_HEADS + h)) * T_SEQ + t) * HDIM + hd] = f2bf(v);
                    }
                }
            }
        }
    }
}

__global__ __launch_bounds__(256) void gemm_qkv(
    const unsigned short* __restrict__ A,
    const unsigned short* __restrict__ Wq, const unsigned short* __restrict__ Wk,
    const unsigned short* __restrict__ Wv,
    const float* __restrict__ bq, const float* __restrict__ bk, const float* __restrict__ bv,
    unsigned short* __restrict__ Q, unsigned short* __restrict__ K,
    unsigned short* __restrict__ V)
{
    const unsigned short* W; const float* b; unsigned short* O; int mode;
    if (blockIdx.z == 0)      { W = Wq; b = bq; O = Q; mode = 0; }
    else if (blockIdx.z == 1) { W = Wk; b = bk; O = K; mode = 0; }
    else                      { W = Wv; b = bv; O = V; mode = 1; }
    gemm_body(A, W, b, O, nullptr, mode);
}

__global__ __launch_bounds__(256) void gemm_out_k(
    const unsigned short* __restrict__ A, const unsigned short* __restrict__ W,
    const float* __restrict__ bias, float* __restrict__ O)
{
    gemm_body(A, W, bias, nullptr, O, 2);
}

// ---------------------------------------------------------------------------
// Kernel 2: FUSED flash attention (no split-K, no combine, no Opart traffic).
// One block per (bh, q-tile); bx = 15 - blockIdx.x so the longest causal
// blocks dispatch first. No-max softmax (S bounded -> exp fp32-safe):
// - bias: 1 LDS read per ct ((qrow>>3) is constant per (wave,quad))
// - l-sum shuffle-reduction deferred to AFTER the k-loop (plain sum)
// Writes Y bf16 (B,T,C) directly.
// ---------------------------------------------------------------------------
__global__ __launch_bounds__(256) void attn_fused(
    const unsigned short* __restrict__ Q, const unsigned short* __restrict__ K,
    const unsigned short* __restrict__ Vt, const float* __restrict__ attn_bias,
    unsigned short* __restrict__ Y)
{
    __shared__ __align__(16) unsigned short Kl[64 * 72];
    __shared__ __align__(16) unsigned short Vl[64 * 72];     // [hd][key]
    __shared__ __align__(16) unsigned short Pl[4][16 * 72];
    __shared__ float biasl[8][64];

    const int tid  = threadIdx.x;
    const int w    = tid >> 6;
    const int lane = tid & 63;
    const int quad = lane >> 4;
    const int l16  = lane & 15;
    const int bx   = 15 - blockIdx.x;   // long blocks first
    const int bh   = blockIdx.y;
    const int h    = bh & 7;
    const int q0   = bx * 64;
    const bool use_bias = (q0 < 512);
    const int brow = 2 * w + (quad >> 1);   // bias row, constant per lane

    if (use_bias) {
        for (int i = tid; i < 512; i += 256) {
            int nq = (q0 >> 3) + (i >> 6);
            biasl[i >> 6][i & 63] = attn_bias[h * 4096 + nq * 64 + (i & 63)];
        }
    }

    const unsigned short* Qbh = Q  + (long)bh * T_SEQ * HDIM;
    const unsigned short* Kbh = K  + (long)bh * T_SEQ * HDIM;
    const unsigned short* Vbh = Vt + (long)bh * HDIM * T_SEQ;   // [hd][t]

    short8 qf[2];
    {
        int qr = q0 + 16 * w + l16;
        qf[0] = *(const short8*)&Qbh[(long)qr * HDIM + 8 * quad];
        qf[1] = *(const short8*)&Qbh[(long)qr * HDIM + 32 + 8 * quad];
    }

    f32x4 oacc[4] = {};
    float lrow[4] = {0.f, 0.f, 0.f, 0.f};
    const int qrb = q0 + 16 * w + 4 * quad;

    for (int kt = 0; kt <= bx; ++kt) {
        const int k0 = kt * 64;
        __syncthreads();
        for (int it = 0; it < 2; ++it) {
            int ch = tid + 256 * it;
            int r = ch >> 3, c8 = ch & 7;
            *(short8*)&Kl[r * 72 + c8 * 8] =
                *(const short8*)&Kbh[(long)(k0 + r) * HDIM + c8 * 8];
            *(short8*)&Vl[r * 72 + c8 * 8] =
                *(const short8*)&Vbh[(long)r * T_SEQ + k0 + c8 * 8];
        }
        __syncthreads();

        // S = Q K^T  (16 x 64 per wave)
        f32x4 s[4] = {};
        for (int st = 0; st < 2; ++st) {
            for (int ct = 0; ct < 4; ++ct) {
                short8 bf = *(const short8*)&Kl[(16 * ct + l16) * 72 + 32 * st + 8 * quad];
                s[ct] = __builtin_amdgcn_mfma_f32_16x16x32_bf16(qf[st], bf, s[ct], 0, 0, 0);
            }
        }

        // P = exp(S*scale + bias) with masking; per-lane partial row sums
        const bool diag = (kt == bx);
        const bool addb = use_bias && (kt < 8);      // keys < 512, block-uniform
        const bool colkeep = (l16 != 15);            // kcol & 15 == l16
        for (int ct = 0; ct < 4; ++ct) {
            int kcol = k0 + 16 * ct + l16;
            float bval = addb ? biasl[brow][(k0 >> 3) + 2 * ct + (l16 >> 3)] : 0.f;
            for (int reg = 0; reg < 4; ++reg) {
                float v = s[ct][reg] * 0.125f + bval;
                bool keep = colkeep && (!diag || (kcol <= qrb + reg));
                float p = keep ? __expf(v) : 0.f;
                lrow[reg] += p;
                Pl[w][(4 * quad + reg) * 72 + 16 * ct + l16] = f2bf(p);
            }
        }

        // O += P V
        for (int st = 0; st < 2; ++st) {
            short8 af = *(const short8*)&Pl[w][l16 * 72 + 32 * st + 8 * quad];
            for (int ct = 0; ct < 4; ++ct) {
                short8 bf = *(const short8*)&Vl[(16 * ct + l16) * 72 + 32 * st + 8 * quad];
                oacc[ct] = __builtin_amdgcn_mfma_f32_16x16x32_bf16(af, bf, oacc[ct], 0, 0, 0);
            }
        }
    }

    // single deferred l-reduction across the 16 lanes of each row group
    for (int off = 1; off < 16; off <<= 1)
        for (int reg = 0; reg < 4; ++reg)
            lrow[reg] += __shfl_xor(lrow[reg], off);

    // epilogue: Y bf16 (B,T,C), normalized
    const int b = bh >> 3;
    for (int reg = 0; reg < 4; ++reg) {
        int qrow = qrb + reg;
        float inv = 1.f / lrow[reg];
        unsigned short* y = Y + ((long)b * T_SEQ + qrow) * C_DIM + h * HDIM;
        for (int ct = 0; ct < 4; ++ct)
            y[16 * ct + l16] = f2bf(oacc[ct][reg] * inv);
    }
}

// ---------------------------------------------------------------------------
extern "C" void kernel_launch(void* const* d_in, const int* in_sizes, int n_in,
                              void* d_out, int out_size, void* d_ws, size_t ws_size,
                              hipStream_t stream)
{
    const float* x         = (const float*)d_in[0];
    const float* attn_bias = (const float*)d_in[1];
    const float* Wq = (const float*)d_in[2]; const float* bq = (const float*)d_in[3];
    const float* Wk = (const float*)d_in[4]; const float* bk = (const float*)d_in[5];
    const float* Wv = (const float*)d_in[6]; const float* bv = (const float*)d_in[7];
    const float* Wp = (const float*)d_in[8]; const float* bp = (const float*)d_in[9];
    float* out = (float*)d_out;

    const long NX = (long)M_ROWS * C_DIM;    // 2,097,152
    const long NW = (long)C_DIM * C_DIM;     // 262,144

    unsigned short* xb  = (unsigned short*)d_ws;
    unsigned short* wqb = xb  + NX;
    unsigned short* wkb = wqb + NW;
    unsigned short* wvb = wkb + NW;
    unsigned short* wpb = wvb + NW;
    unsigned short* Qb  = wpb + NW;
    unsigned short* Kb  = Qb  + NX;
    unsigned short* Vtb = Kb  + NX;          // transposed (B,H,HD,T)
    unsigned short* Yb  = Vtb + NX;

    long n4 = (NX + 4 * NW) / 4;
    cast_all<<<dim3((unsigned)(n4 / 256)), 256, 0, stream>>>(
        x, Wq, Wk, Wv, Wp, xb, wqb, wkb, wvb, wpb);

    gemm_qkv<<<dim3(M_ROWS / 128, C_DIM / 128, 3), 256, 0, stream>>>(
        xb, wqb, wkb, wvb, bq, bk, bv, Qb, Kb, Vtb);

    attn_fused<<<dim3(T_SEQ / 64, B_BATCH * H_HEADS), 256, 0, stream>>>(
        Qb, Kb, Vtb, attn_bias, Yb);

    gemm_out_k<<<dim3(M_ROWS / 128, C_DIM / 128), 256, 0, stream>>>(
        Yb, wpb, bp, out);
}

// Round 9
// 133.964 us; speedup vs baseline: 1.1118x; 1.1118x over previous
//
#include <hip/hip_runtime.h>

#define T_SEQ 1024
#define C_DIM 512
#define H_HEADS 8
#define HDIM 64
#define B_BATCH 4
#define M_ROWS (B_BATCH * T_SEQ)   // 4096
#define NSPLIT_TOT 40              // sum over bx of ceil((bx+1)/4)

typedef __attribute__((ext_vector_type(8))) short short8;
typedef __attribute__((ext_vector_type(4))) float f32x4;

__device__ __forceinline__ unsigned short f2bf(float f) {
    unsigned u = __builtin_bit_cast(unsigned, f);
    u += 0x7FFFu + ((u >> 16) & 1u);   // round-to-nearest-even
    return (unsigned short)(u >> 16);
}

// async global->LDS, 16B per lane; LDS dest = uniform base + lane*16
__device__ __forceinline__ void gload_lds16(const unsigned short* g, unsigned short* l) {
    __builtin_amdgcn_global_load_lds(
        (const __attribute__((address_space(1))) unsigned int*)(const void*)g,
        (__attribute__((address_space(3))) unsigned int*)(void*)l, 16, 0, 0);
}

__device__ __constant__ unsigned char BX_OF[NSPLIT_TOT] =
    {0,1,2,3,4,4,5,5,6,6,7,7,8,8,8,9,9,9,10,10,10,11,11,11,
     12,12,12,12,13,13,13,13,14,14,14,14,15,15,15,15};
__device__ __constant__ unsigned char SP_OF[NSPLIT_TOT] =
    {0,0,0,0,0,1,0,1,0,1,0,1,0,1,2,0,1,2,0,1,2,0,1,2,
     0,1,2,3,0,1,2,3,0,1,2,3,0,1,2,3};
__device__ __constant__ unsigned char CUM_OF[16] =
    {0,1,2,3,4,6,8,10,12,15,18,21,24,28,32,36};

// ---------------------------------------------------------------------------
// Kernel 1: one-shot cast of x + 4 weight matrices to bf16 (r4/r5: fusing the
// cast into GEMM staging costs ~196 MB of per-block fp32 re-reads — never).
// ---------------------------------------------------------------------------
__global__ __launch_bounds__(256) void cast_all(
    const float* __restrict__ x,
    const float* __restrict__ wq, const float* __restrict__ wk,
    const float* __restrict__ wv, const float* __restrict__ wp,
    unsigned short* __restrict__ xb,
    unsigned short* __restrict__ wqb, unsigned short* __restrict__ wkb,
    unsigned short* __restrict__ wvb, unsigned short* __restrict__ wpb)
{
    const long NX = (long)M_ROWS * C_DIM;
    const long NW = (long)C_DIM * C_DIM;
    long i4 = (long)blockIdx.x * blockDim.x + threadIdx.x;
    long base = i4 * 4;
    const float* src; unsigned short* dst; long off;
    if (base < NX) { src = x; dst = xb; off = base; }
    else {
        long r = base - NX;
        int w = (int)(r >> 18);
        off = r & (NW - 1);
        switch (w) {
            case 0:  src = wq; dst = wqb; break;
            case 1:  src = wk; dst = wkb; break;
            case 2:  src = wv; dst = wvb; break;
            default: src = wp; dst = wpb; break;
        }
    }
    float4 v = *(const float4*)(src + off);
    ushort4 o;
    o.x = f2bf(v.x); o.y = f2bf(v.y); o.z = f2bf(v.z); o.w = f2bf(v.w);
    *(ushort4*)(dst + off) = o;
}

// ---------------------------------------------------------------------------
// m97-style GEMM (r3/r6, known-good): O = A(M x 512) @ W^T(512 x 512) + b.
// 128x128 tile, 256 threads. global_load_lds width=16, unpadded LDS with XOR
// chunk swizzle. mode 0: bf16 (B,H,T,HD); mode 1: bf16 (B,H,HD,T) via swapped
// MFMA operands; mode 2: fp32 M x N.
// ---------------------------------------------------------------------------
__device__ __forceinline__ void gemm_body(
    const unsigned short* __restrict__ A,
    const unsigned short* __restrict__ W,
    const float* __restrict__ bias,
    unsigned short* __restrict__ Obf,
    float* __restrict__ Of,
    int mode)
{
    __shared__ __align__(16) unsigned short Atile[128 * 64];
    __shared__ __align__(16) unsigned short Btile[128 * 64];

    const int tid  = threadIdx.x;
    const int w    = tid >> 6;
    const int lane = tid & 63;
    const int quad = lane >> 4;
    const int l16  = lane & 15;
    const int m0   = blockIdx.x * 128;
    const int n0   = blockIdx.y * 128;
    const int wr   = 64 * (w >> 1);
    const int wc   = 64 * (w & 1);

    f32x4 acc[4][4] = {};

    const int lr = lane >> 3;
    const int lc = lane & 7;

    for (int k0 = 0; k0 < 512; k0 += 64) {
        __syncthreads();
        for (int i = 0; i < 4; ++i) {
            int r0 = 32 * w + 8 * i;
            int r  = r0 + lr;
            int c  = lc ^ (r & 7);      // XOR swizzle
            gload_lds16(&A[(long)(m0 + r) * 512 + k0 + c * 8], &Atile[r0 * 64]);
            gload_lds16(&W[(long)(n0 + r) * 512 + k0 + c * 8], &Btile[r0 * 64]);
        }
        __syncthreads();

        for (int st = 0; st < 2; ++st) {
            const int pc = ((4 * st + quad) ^ (l16 & 7)) * 8;
            short8 af[4], bf[4];
            for (int i = 0; i < 4; ++i)
                af[i] = *(const short8*)&Atile[(wr + 16 * i + l16) * 64 + pc];
            for (int j = 0; j < 4; ++j)
                bf[j] = *(const short8*)&Btile[(wc + 16 * j + l16) * 64 + pc];
            for (int i = 0; i < 4; ++i)
                for (int j = 0; j < 4; ++j)
                    acc[i][j] = (mode == 1)
                        ? __builtin_amdgcn_mfma_f32_16x16x32_bf16(bf[j], af[i], acc[i][j], 0, 0, 0)
                        : __builtin_amdgcn_mfma_f32_16x16x32_bf16(af[i], bf[j], acc[i][j], 0, 0, 0);
        }
    }

    if (mode == 1) {
        for (int j = 0; j < 4; ++j) {
            for (int reg = 0; reg < 4; ++reg) {
                int n = n0 + wc + 16 * j + 4 * quad + reg;
                int h = n >> 6, hd = n & 63;
                float bv = bias[n];
                for (int i = 0; i < 4; ++i) {
                    int t = m0 + wr + 16 * i + l16;
                    int b = t >> 10, tl = t & 1023;
                    Obf[(((long)(b * H_HEADS + h)) * HDIM + hd) * T_SEQ + tl] =
                        f2bf(acc[i][j][reg] + bv);
                }
            }
        }
    } else {
        for (int j = 0; j < 4; ++j) {
            int col = n0 + wc + 16 * j + l16;
            float bv = bias[col];
            for (int i = 0; i < 4; ++i) {
                for (int reg = 0; reg < 4; ++reg) {
                    int row = m0 + wr + 16 * i + 4 * quad + reg;
                    float v = acc[i][j][reg] + bv;
                    if (mode == 2) {
                        Of[(long)row * 512 + col] = v;
                    } else {
                        int b = row >> 10, t = row & 1023;
                        int h = col >> 6,  hd = col & 63;
                        Obf[(((long)(b * H_HEADS + h)) * T_SEQ + t) * HDIM + hd] = f2bf(v);
                    }
                }
            }
        }
    }
}

__global__ __launch_bounds__(256) void gemm_qkv(
    const unsigned short* __restrict__ A,
    const unsigned short* __restrict__ Wq, const unsigned short* __restrict__ Wk,
    const unsigned short* __restrict__ Wv,
    const float* __restrict__ bq, const float* __restrict__ bk, const float* __restrict__ bv,
    unsigned short* __restrict__ Q, unsigned short* __restrict__ K,
    unsigned short* __restrict__ V)
{
    const unsigned short* W; const float* b; unsigned short* O; int mode;
    if (blockIdx.z == 0)      { W = Wq; b = bq; O = Q; mode = 0; }
    else if (blockIdx.z == 1) { W = Wk; b = bk; O = K; mode = 0; }
    else                      { W = Wv; b = bv; O = V; mode = 1; }
    gemm_body(A, W, b, O, nullptr, mode);
}

__global__ __launch_bounds__(256) void gemm_out_k(
    const unsigned short* __restrict__ A, const unsigned short* __restrict__ W,
    const float* __restrict__ bias, float* __restrict__ O)
{
    gemm_body(A, W, bias, nullptr, O, 2);
}

// ---------------------------------------------------------------------------
// Kernel 3a: split-K flash attention, no-max softmax, slim inner loop:
// - l-sum shuffle-reduction DEFERRED to after the k-loop (plain sum)
// - bias: 1 LDS read per ct ((qrb+reg)>>3 is reg-independent: 4*(quad&1)+reg<8)
// - lane-static column mask (kcol&15 == l16)
// 1280 blocks (40 splits x 32 bh), each <= 4 key tiles -> 5 blocks/CU, balanced.
// ---------------------------------------------------------------------------
__global__ __launch_bounds__(256) void attn_split(
    const unsigned short* __restrict__ Q, const unsigned short* __restrict__ K,
    const unsigned short* __restrict__ Vt, const float* __restrict__ attn_bias,
    float* __restrict__ Opart, float* __restrict__ lpart)
{
    __shared__ __align__(16) unsigned short Kl[64 * 72];
    __shared__ __align__(16) unsigned short Vl[64 * 72];     // [hd][key]
    __shared__ __align__(16) unsigned short Pl[4][16 * 72];
    __shared__ float biasl[8][64];

    const int tid  = threadIdx.x;
    const int w    = tid >> 6;
    const int lane = tid & 63;
    const int quad = lane >> 4;
    const int l16  = lane & 15;
    const int sidx = blockIdx.x;
    const int bh   = blockIdx.y;
    const int h    = bh & 7;
    const int bx   = BX_OF[sidx];
    const int sp   = SP_OF[sidx];
    const int q0   = bx * 64;
    const int kt0  = sp * 4;
    const int kt1  = min(kt0 + 4, bx + 1);
    const bool use_bias = (q0 < 512) && (sp < 2);   // block-uniform
    const int brow = 2 * w + (quad >> 1);           // bias row, constant per lane
    const int bcol0 = 2 * 0 + (l16 >> 3);           // + 2*ct + (k0>>3)

    if (use_bias) {
        for (int i = tid; i < 512; i += 256) {
            int nq = (q0 >> 3) + (i >> 6);
            biasl[i >> 6][i & 63] = attn_bias[h * 4096 + nq * 64 + (i & 63)];
        }
    }

    const unsigned short* Qbh = Q  + (long)bh * T_SEQ * HDIM;
    const unsigned short* Kbh = K  + (long)bh * T_SEQ * HDIM;
    const unsigned short* Vbh = Vt + (long)bh * HDIM * T_SEQ;   // [hd][t]

    short8 qf[2];
    {
        int qr = q0 + 16 * w + l16;
        qf[0] = *(const short8*)&Qbh[(long)qr * HDIM + 8 * quad];
        qf[1] = *(const short8*)&Qbh[(long)qr * HDIM + 32 + 8 * quad];
    }

    f32x4 oacc[4] = {};
    float lrow[4] = {0.f, 0.f, 0.f, 0.f};
    const int qrb = q0 + 16 * w + 4 * quad;
    const bool colkeep = (l16 != 15);               // kcol & 15 == l16

    for (int kt = kt0; kt < kt1; ++kt) {
        const int k0 = kt * 64;
        __syncthreads();
        for (int it = 0; it < 2; ++it) {
            int ch = tid + 256 * it;
            int r = ch >> 3, c8 = ch & 7;
            *(short8*)&Kl[r * 72 + c8 * 8] =
                *(const short8*)&Kbh[(long)(k0 + r) * HDIM + c8 * 8];
            *(short8*)&Vl[r * 72 + c8 * 8] =
                *(const short8*)&Vbh[(long)r * T_SEQ + k0 + c8 * 8];
        }
        __syncthreads();

        // S = Q K^T  (16 x 64 per wave)
        f32x4 s[4] = {};
        for (int st = 0; st < 2; ++st) {
            for (int ct = 0; ct < 4; ++ct) {
                short8 bf = *(const short8*)&Kl[(16 * ct + l16) * 72 + 32 * st + 8 * quad];
                s[ct] = __builtin_amdgcn_mfma_f32_16x16x32_bf16(qf[st], bf, s[ct], 0, 0, 0);
            }
        }

        // P = exp(S*scale + bias) with masking; per-lane partial row sums
        const bool diag = (kt == bx);
        for (int ct = 0; ct < 4; ++ct) {
            int kcol = k0 + 16 * ct + l16;
            float bval = use_bias ? biasl[brow][(k0 >> 3) + 2 * ct + bcol0] : 0.f;
            for (int reg = 0; reg < 4; ++reg) {
                float v = s[ct][reg] * 0.125f + bval;
                bool keep = colkeep && (!diag || (kcol <= qrb + reg));
                float p = keep ? __expf(v) : 0.f;
                lrow[reg] += p;
                Pl[w][(4 * quad + reg) * 72 + 16 * ct + l16] = f2bf(p);
            }
        }

        // O += P V
        for (int st = 0; st < 2; ++st) {
            short8 af = *(const short8*)&Pl[w][l16 * 72 + 32 * st + 8 * quad];
            for (int ct = 0; ct < 4; ++ct) {
                short8 bf = *(const short8*)&Vl[(16 * ct + l16) * 72 + 32 * st + 8 * quad];
                oacc[ct] = __builtin_amdgcn_mfma_f32_16x16x32_bf16(af, bf, oacc[ct], 0, 0, 0);
            }
        }
    }

    // single deferred l-reduction across the 16 lanes of each row group
    for (int off = 1; off < 16; off <<= 1)
        for (int reg = 0; reg < 4; ++reg)
            lrow[reg] += __shfl_xor(lrow[reg], off);

    // partial epilogue (unnormalized)
    const long p = (long)bh * NSPLIT_TOT + sidx;
    float* Op = Opart + p * 4096;
    for (int ct = 0; ct < 4; ++ct)
        for (int reg = 0; reg < 4; ++reg)
            Op[(16 * w + 4 * quad + reg) * 64 + 16 * ct + l16] = oacc[ct][reg];
    if (l16 == 0) {
        for (int reg = 0; reg < 4; ++reg) {
            int qr = 16 * w + 4 * quad + reg;
            lpart[p * 64 + qr] = lrow[reg];
        }
    }
}

// ---------------------------------------------------------------------------
// Kernel 3b: combine splits (plain sum), normalize, write Y bf16 (B,T,C)
// ---------------------------------------------------------------------------
__global__ __launch_bounds__(256) void attn_combine(
    const float* __restrict__ Opart, const float* __restrict__ lpart,
    unsigned short* __restrict__ Y)
{
    const int bx = blockIdx.x, bh = blockIdx.y;
    const int b = bh >> 3, h = bh & 7;
    const int ns = (bx >> 2) + 1;
    const long p0 = (long)bh * NSPLIT_TOT + CUM_OF[bx];
    const int tid = threadIdx.x;
    const int qr = tid >> 2;
    const int hs = (tid & 3) * 16;

    float L = 0.f;
    for (int s = 0; s < ns; ++s) L += lpart[(p0 + s) * 64 + qr];

    float acc[16] = {};
    for (int s = 0; s < ns; ++s) {
        const float4* op = (const float4*)(Opart + (p0 + s) * 4096 + qr * 64 + hs);
        for (int j4 = 0; j4 < 4; ++j4) {
            float4 v = op[j4];
            acc[4 * j4 + 0] += v.x; acc[4 * j4 + 1] += v.y;
            acc[4 * j4 + 2] += v.z; acc[4 * j4 + 3] += v.w;
        }
    }
    float inv = 1.f / L;
    int q = bx * 64 + qr;
    unsigned short* y = Y + ((long)b * T_SEQ + q) * C_DIM + h * HDIM + hs;
    for (int j4 = 0; j4 < 4; ++j4) {
        ushort4 o;
        o.x = f2bf(acc[4 * j4 + 0] * inv); o.y = f2bf(acc[4 * j4 + 1] * inv);
        o.z = f2bf(acc[4 * j4 + 2] * inv); o.w = f2bf(acc[4 * j4 + 3] * inv);
        *(ushort4*)(y + 4 * j4) = o;
    }
}

// ---------------------------------------------------------------------------
extern "C" void kernel_launch(void* const* d_in, const int* in_sizes, int n_in,
                              void* d_out, int out_size, void* d_ws, size_t ws_size,
                              hipStream_t stream)
{
    const float* x         = (const float*)d_in[0];
    const float* attn_bias = (const float*)d_in[1];
    const float* Wq = (const float*)d_in[2]; const float* bq = (const float*)d_in[3];
    const float* Wk = (const float*)d_in[4]; const float* bk = (const float*)d_in[5];
    const float* Wv = (const float*)d_in[6]; const float* bv = (const float*)d_in[7];
    const float* Wp = (const float*)d_in[8]; const float* bp = (const float*)d_in[9];
    float* out = (float*)d_out;

    const long NX = (long)M_ROWS * C_DIM;    // 2,097,152
    const long NW = (long)C_DIM * C_DIM;     // 262,144

    unsigned short* xb  = (unsigned short*)d_ws;
    unsigned short* wqb = xb  + NX;
    unsigned short* wkb = wqb + NW;
    unsigned short* wvb = wkb + NW;
    unsigned short* wpb = wvb + NW;
    unsigned short* Qb  = wpb + NW;
    unsigned short* Kb  = Qb  + NX;
    unsigned short* Vtb = Kb  + NX;          // transposed (B,H,HD,T)
    unsigned short* Yb  = Vtb + NX;
    float* Opart = (float*)(Yb + NX);        // 32*40 x 64x64 fp32 = 21 MB
    float* lpart = Opart + (long)32 * NSPLIT_TOT * 4096;

    long n4 = (NX + 4 * NW) / 4;
    cast_all<<<dim3((unsigned)(n4 / 256)), 256, 0, stream>>>(
        x, Wq, Wk, Wv, Wp, xb, wqb, wkb, wvb, wpb);

    gemm_qkv<<<dim3(M_ROWS / 128, C_DIM / 128, 3), 256, 0, stream>>>(
        xb, wqb, wkb, wvb, bq, bk, bv, Qb, Kb, Vtb);

    attn_split<<<dim3(NSPLIT_TOT, B_BATCH * H_HEADS), 256, 0, stream>>>(
        Qb, Kb, Vtb, attn_bias, Opart, lpart);

    attn_combine<<<dim3(T_SEQ / 64, B_BATCH * H_HEADS), 256, 0, stream>>>(
        Opart, lpart, Yb);

    gemm_out_k<<<dim3(M_ROWS / 128, C_DIM / 128), 256, 0, stream>>>(
        Yb, wpb, bp, out);
}

// Round 10
// 133.793 us; speedup vs baseline: 1.1132x; 1.0013x over previous
//
#include <hip/hip_runtime.h>

#define T_SEQ 1024
#define C_DIM 512
#define H_HEADS 8
#define HDIM 64
#define B_BATCH 4
#define M_ROWS (B_BATCH * T_SEQ)   // 4096
#define NSPLIT_TOT 40              // sum over bx of ceil((bx+1)/4)

typedef __attribute__((ext_vector_type(8))) short short8;
typedef __attribute__((ext_vector_type(4))) float f32x4;

__device__ __forceinline__ unsigned short f2bf(float f) {
    unsigned u = __builtin_bit_cast(unsigned, f);
    u += 0x7FFFu + ((u >> 16) & 1u);   // round-to-nearest-even
    return (unsigned short)(u >> 16);
}

__device__ __forceinline__ float bf2f(unsigned short u) {
    return __builtin_bit_cast(float, (unsigned)u << 16);
}

// async global->LDS, 16B per lane; LDS dest = uniform base + lane*16
__device__ __forceinline__ void gload_lds16(const unsigned short* g, unsigned short* l) {
    __builtin_amdgcn_global_load_lds(
        (const __attribute__((address_space(1))) unsigned int*)(const void*)g,
        (__attribute__((address_space(3))) unsigned int*)(void*)l, 16, 0, 0);
}

__device__ __constant__ unsigned char BX_OF[NSPLIT_TOT] =
    {0,1,2,3,4,4,5,5,6,6,7,7,8,8,8,9,9,9,10,10,10,11,11,11,
     12,12,12,12,13,13,13,13,14,14,14,14,15,15,15,15};
__device__ __constant__ unsigned char SP_OF[NSPLIT_TOT] =
    {0,0,0,0,0,1,0,1,0,1,0,1,0,1,2,0,1,2,0,1,2,0,1,2,
     0,1,2,3,0,1,2,3,0,1,2,3,0,1,2,3};
__device__ __constant__ unsigned char CUM_OF[16] =
    {0,1,2,3,4,6,8,10,12,15,18,21,24,28,32,36};

// ---------------------------------------------------------------------------
// Kernel 1: one-shot cast of x + 4 weight matrices to bf16 (r4/r5: fusing the
// cast into GEMM staging costs ~196 MB of per-block fp32 re-reads — never).
// ---------------------------------------------------------------------------
__global__ __launch_bounds__(256) void cast_all(
    const float* __restrict__ x,
    const float* __restrict__ wq, const float* __restrict__ wk,
    const float* __restrict__ wv, const float* __restrict__ wp,
    unsigned short* __restrict__ xb,
    unsigned short* __restrict__ wqb, unsigned short* __restrict__ wkb,
    unsigned short* __restrict__ wvb, unsigned short* __restrict__ wpb)
{
    const long NX = (long)M_ROWS * C_DIM;
    const long NW = (long)C_DIM * C_DIM;
    long i4 = (long)blockIdx.x * blockDim.x + threadIdx.x;
    long base = i4 * 4;
    const float* src; unsigned short* dst; long off;
    if (base < NX) { src = x; dst = xb; off = base; }
    else {
        long r = base - NX;
        int w = (int)(r >> 18);
        off = r & (NW - 1);
        switch (w) {
            case 0:  src = wq; dst = wqb; break;
            case 1:  src = wk; dst = wkb; break;
            case 2:  src = wv; dst = wvb; break;
            default: src = wp; dst = wpb; break;
        }
    }
    float4 v = *(const float4*)(src + off);
    ushort4 o;
    o.x = f2bf(v.x); o.y = f2bf(v.y); o.z = f2bf(v.z); o.w = f2bf(v.w);
    *(ushort4*)(dst + off) = o;
}

// ---------------------------------------------------------------------------
// m97-style GEMM (r3/r6, known-good): O = A(M x 512) @ W^T(512 x 512) + b.
// 128x128 tile, 256 threads. global_load_lds width=16, unpadded LDS with XOR
// chunk swizzle. mode 0: bf16 (B,H,T,HD); mode 1: bf16 (B,H,HD,T) via swapped
// MFMA operands; mode 2: fp32 M x N.
// ---------------------------------------------------------------------------
__device__ __forceinline__ void gemm_body(
    const unsigned short* __restrict__ A,
    const unsigned short* __restrict__ W,
    const float* __restrict__ bias,
    unsigned short* __restrict__ Obf,
    float* __restrict__ Of,
    int mode)
{
    __shared__ __align__(16) unsigned short Atile[128 * 64];
    __shared__ __align__(16) unsigned short Btile[128 * 64];

    const int tid  = threadIdx.x;
    const int w    = tid >> 6;
    const int lane = tid & 63;
    const int quad = lane >> 4;
    const int l16  = lane & 15;
    const int m0   = blockIdx.x * 128;
    const int n0   = blockIdx.y * 128;
    const int wr   = 64 * (w >> 1);
    const int wc   = 64 * (w & 1);

    f32x4 acc[4][4] = {};

    const int lr = lane >> 3;
    const int lc = lane & 7;

    for (int k0 = 0; k0 < 512; k0 += 64) {
        __syncthreads();
        for (int i = 0; i < 4; ++i) {
            int r0 = 32 * w + 8 * i;
            int r  = r0 + lr;
            int c  = lc ^ (r & 7);      // XOR swizzle
            gload_lds16(&A[(long)(m0 + r) * 512 + k0 + c * 8], &Atile[r0 * 64]);
            gload_lds16(&W[(long)(n0 + r) * 512 + k0 + c * 8], &Btile[r0 * 64]);
        }
        __syncthreads();

        for (int st = 0; st < 2; ++st) {
            const int pc = ((4 * st + quad) ^ (l16 & 7)) * 8;
            short8 af[4], bf[4];
            for (int i = 0; i < 4; ++i)
                af[i] = *(const short8*)&Atile[(wr + 16 * i + l16) * 64 + pc];
            for (int j = 0; j < 4; ++j)
                bf[j] = *(const short8*)&Btile[(wc + 16 * j + l16) * 64 + pc];
            for (int i = 0; i < 4; ++i)
                for (int j = 0; j < 4; ++j)
                    acc[i][j] = (mode == 1)
                        ? __builtin_amdgcn_mfma_f32_16x16x32_bf16(bf[j], af[i], acc[i][j], 0, 0, 0)
                        : __builtin_amdgcn_mfma_f32_16x16x32_bf16(af[i], bf[j], acc[i][j], 0, 0, 0);
        }
    }

    if (mode == 1) {
        for (int j = 0; j < 4; ++j) {
            for (int reg = 0; reg < 4; ++reg) {
                int n = n0 + wc + 16 * j + 4 * quad + reg;
                int h = n >> 6, hd = n & 63;
                float bv = bias[n];
                for (int i = 0; i < 4; ++i) {
                    int t = m0 + wr + 16 * i + l16;
                    int b = t >> 10, tl = t & 1023;
                    Obf[(((long)(b * H_HEADS + h)) * HDIM + hd) * T_SEQ + tl] =
                        f2bf(acc[i][j][reg] + bv);
                }
            }
        }
    } else {
        for (int j = 0; j < 4; ++j) {
            int col = n0 + wc + 16 * j + l16;
            float bv = bias[col];
            for (int i = 0; i < 4; ++i) {
                for (int reg = 0; reg < 4; ++reg) {
                    int row = m0 + wr + 16 * i + 4 * quad + reg;
                    float v = acc[i][j][reg] + bv;
                    if (mode == 2) {
                        Of[(long)row * 512 + col] = v;
                    } else {
                        int b = row >> 10, t = row & 1023;
                        int h = col >> 6,  hd = col & 63;
                        Obf[(((long)(b * H_HEADS + h)) * T_SEQ + t) * HDIM + hd] = f2bf(v);
                    }
                }
            }
        }
    }
}

__global__ __launch_bounds__(256) void gemm_qkv(
    const unsigned short* __restrict__ A,
    const unsigned short* __restrict__ Wq, const unsigned short* __restrict__ Wk,
    const unsigned short* __restrict__ Wv,
    const float* __restrict__ bq, const float* __restrict__ bk, const float* __restrict__ bv,
    unsigned short* __restrict__ Q, unsigned short* __restrict__ K,
    unsigned short* __restrict__ V)
{
    const unsigned short* W; const float* b; unsigned short* O; int mode;
    if (blockIdx.z == 0)      { W = Wq; b = bq; O = Q; mode = 0; }
    else if (blockIdx.z == 1) { W = Wk; b = bk; O = K; mode = 0; }
    else                      { W = Wv; b = bv; O = V; mode = 1; }
    gemm_body(A, W, b, O, nullptr, mode);
}

__global__ __launch_bounds__(256) void gemm_out_k(
    const unsigned short* __restrict__ A, const unsigned short* __restrict__ W,
    const float* __restrict__ bias, float* __restrict__ O)
{
    gemm_body(A, W, bias, nullptr, O, 2);
}

// ---------------------------------------------------------------------------
// Kernel 3a: split-K flash attention, no-max softmax, slim inner loop (r9) +
// ASYNC K/V staging: global_load_lds width=16 into unpadded 64x64 tiles with
// the gemm_body XOR chunk swizzle (no VGPR round-trip in the serial chain).
// Partials now stored bf16 (Y is bf16 anyway; one extra ~0.4% rounding).
// ---------------------------------------------------------------------------
__global__ __launch_bounds__(256) void attn_split(
    const unsigned short* __restrict__ Q, const unsigned short* __restrict__ K,
    const unsigned short* __restrict__ Vt, const float* __restrict__ attn_bias,
    unsigned short* __restrict__ Opart, float* __restrict__ lpart)
{
    __shared__ __align__(16) unsigned short Kl[64 * 64];
    __shared__ __align__(16) unsigned short Vl[64 * 64];     // [hd][key]
    __shared__ __align__(16) unsigned short Pl[4][16 * 72];
    __shared__ float biasl[8][64];

    const int tid  = threadIdx.x;
    const int w    = tid >> 6;
    const int lane = tid & 63;
    const int quad = lane >> 4;
    const int l16  = lane & 15;
    const int lr   = lane >> 3;
    const int lc   = lane & 7;
    const int sidx = blockIdx.x;
    const int bh   = blockIdx.y;
    const int h    = bh & 7;
    const int bx   = BX_OF[sidx];
    const int sp   = SP_OF[sidx];
    const int q0   = bx * 64;
    const int kt0  = sp * 4;
    const int kt1  = min(kt0 + 4, bx + 1);
    const bool use_bias = (q0 < 512) && (sp < 2);   // block-uniform
    const int brow = 2 * w + (quad >> 1);           // bias row, constant per lane
    const int bcol0 = l16 >> 3;                     // + (k0>>3) + 2*ct

    if (use_bias) {
        for (int i = tid; i < 512; i += 256) {
            int nq = (q0 >> 3) + (i >> 6);
            biasl[i >> 6][i & 63] = attn_bias[h * 4096 + nq * 64 + (i & 63)];
        }
    }

    const unsigned short* Qbh = Q  + (long)bh * T_SEQ * HDIM;
    const unsigned short* Kbh = K  + (long)bh * T_SEQ * HDIM;
    const unsigned short* Vbh = Vt + (long)bh * HDIM * T_SEQ;   // [hd][t]

    short8 qf[2];
    {
        int qr = q0 + 16 * w + l16;
        qf[0] = *(const short8*)&Qbh[(long)qr * HDIM + 8 * quad];
        qf[1] = *(const short8*)&Qbh[(long)qr * HDIM + 32 + 8 * quad];
    }

    f32x4 oacc[4] = {};
    float lrow[4] = {0.f, 0.f, 0.f, 0.f};
    const int qrb = q0 + 16 * w + 4 * quad;
    const bool colkeep = (l16 != 15);               // kcol & 15 == l16

    for (int kt = kt0; kt < kt1; ++kt) {
        const int k0 = kt * 64;
        __syncthreads();
        // async staging: wave w covers rows [16w,16w+16), 2 issues x 8 rows,
        // XOR swizzle c = lc ^ (r&7) matches gemm_body's layout
        for (int i = 0; i < 2; ++i) {
            int r0 = 16 * w + 8 * i;
            int r  = r0 + lr;
            int c  = lc ^ (r & 7);
            gload_lds16(&Kbh[(long)(k0 + r) * HDIM + c * 8], &Kl[r0 * 64]);
            gload_lds16(&Vbh[(long)r * T_SEQ + k0 + c * 8], &Vl[r0 * 64]);
        }
        __syncthreads();

        // S = Q K^T  (16 x 64 per wave); swizzled fragment reads
        f32x4 s[4] = {};
        for (int st = 0; st < 2; ++st) {
            const int pc = ((4 * st + quad) ^ (l16 & 7)) * 8;
            for (int ct = 0; ct < 4; ++ct) {
                short8 bf = *(const short8*)&Kl[(16 * ct + l16) * 64 + pc];
                s[ct] = __builtin_amdgcn_mfma_f32_16x16x32_bf16(qf[st], bf, s[ct], 0, 0, 0);
            }
        }

        // P = exp(S*scale + bias) with masking; per-lane partial row sums
        const bool diag = (kt == bx);
        for (int ct = 0; ct < 4; ++ct) {
            int kcol = k0 + 16 * ct + l16;
            float bval = use_bias ? biasl[brow][(k0 >> 3) + 2 * ct + bcol0] : 0.f;
            for (int reg = 0; reg < 4; ++reg) {
                float v = s[ct][reg] * 0.125f + bval;
                bool keep = colkeep && (!diag || (kcol <= qrb + reg));
                float p = keep ? __expf(v) : 0.f;
                lrow[reg] += p;
                Pl[w][(4 * quad + reg) * 72 + 16 * ct + l16] = f2bf(p);
            }
        }

        // O += P V; swizzled V fragment reads
        for (int st = 0; st < 2; ++st) {
            const int pc = ((4 * st + quad) ^ (l16 & 7)) * 8;
            short8 af = *(const short8*)&Pl[w][l16 * 72 + 32 * st + 8 * quad];
            for (int ct = 0; ct < 4; ++ct) {
                short8 bf = *(const short8*)&Vl[(16 * ct + l16) * 64 + pc];
                oacc[ct] = __builtin_amdgcn_mfma_f32_16x16x32_bf16(af, bf, oacc[ct], 0, 0, 0);
            }
        }
    }

    // single deferred l-reduction across the 16 lanes of each row group
    for (int off = 1; off < 16; off <<= 1)
        for (int reg = 0; reg < 4; ++reg)
            lrow[reg] += __shfl_xor(lrow[reg], off);

    // partial epilogue (unnormalized, bf16)
    const long p = (long)bh * NSPLIT_TOT + sidx;
    unsigned short* Op = Opart + p * 4096;
    for (int ct = 0; ct < 4; ++ct)
        for (int reg = 0; reg < 4; ++reg)
            Op[(16 * w + 4 * quad + reg) * 64 + 16 * ct + l16] = f2bf(oacc[ct][reg]);
    if (l16 == 0) {
        for (int reg = 0; reg < 4; ++reg) {
            int qr = 16 * w + 4 * quad + reg;
            lpart[p * 64 + qr] = lrow[reg];
        }
    }
}

// ---------------------------------------------------------------------------
// Kernel 3b: combine bf16 splits (plain sum), normalize, write Y bf16 (B,T,C)
// ---------------------------------------------------------------------------
__global__ __launch_bounds__(256) void attn_combine(
    const unsigned short* __restrict__ Opart, const float* __restrict__ lpart,
    unsigned short* __restrict__ Y)
{
    const int bx = blockIdx.x, bh = blockIdx.y;
    const int b = bh >> 3, h = bh & 7;
    const int ns = (bx >> 2) + 1;
    const long p0 = (long)bh * NSPLIT_TOT + CUM_OF[bx];
    const int tid = threadIdx.x;
    const int qr = tid >> 2;
    const int hs = (tid & 3) * 16;

    float L = 0.f;
    for (int s = 0; s < ns; ++s) L += lpart[(p0 + s) * 64 + qr];

    float acc[16] = {};
    for (int s = 0; s < ns; ++s) {
        const unsigned short* op = Opart + (p0 + s) * 4096 + qr * 64 + hs;
        short8 v0 = *(const short8*)op;
        short8 v1 = *(const short8*)(op + 8);
        for (int k = 0; k < 8; ++k) {
            acc[k]     += bf2f((unsigned short)v0[k]);
            acc[k + 8] += bf2f((unsigned short)v1[k]);
        }
    }
    float inv = 1.f / L;
    int q = bx * 64 + qr;
    unsigned short* y = Y + ((long)b * T_SEQ + q) * C_DIM + h * HDIM + hs;
    for (int j4 = 0; j4 < 4; ++j4) {
        ushort4 o;
        o.x = f2bf(acc[4 * j4 + 0] * inv); o.y = f2bf(acc[4 * j4 + 1] * inv);
        o.z = f2bf(acc[4 * j4 + 2] * inv); o.w = f2bf(acc[4 * j4 + 3] * inv);
        *(ushort4*)(y + 4 * j4) = o;
    }
}

// ---------------------------------------------------------------------------
extern "C" void kernel_launch(void* const* d_in, const int* in_sizes, int n_in,
                              void* d_out, int out_size, void* d_ws, size_t ws_size,
                              hipStream_t stream)
{
    const float* x         = (const float*)d_in[0];
    const float* attn_bias = (const float*)d_in[1];
    const float* Wq = (const float*)d_in[2]; const float* bq = (const float*)d_in[3];
    const float* Wk = (const float*)d_in[4]; const float* bk = (const float*)d_in[5];
    const float* Wv = (const float*)d_in[6]; const float* bv = (const float*)d_in[7];
    const float* Wp = (const float*)d_in[8]; const float* bp = (const float*)d_in[9];
    float* out = (float*)d_out;

    const long NX = (long)M_ROWS * C_DIM;    // 2,097,152
    const long NW = (long)C_DIM * C_DIM;     // 262,144

    unsigned short* xb  = (unsigned short*)d_ws;
    unsigned short* wqb = xb  + NX;
    unsigned short* wkb = wqb + NW;
    unsigned short* wvb = wkb + NW;
    unsigned short* wpb = wvb + NW;
    unsigned short* Qb  = wpb + NW;
    unsigned short* Kb  = Qb  + NX;
    unsigned short* Vtb = Kb  + NX;          // transposed (B,H,HD,T)
    unsigned short* Yb  = Vtb + NX;
    unsigned short* Opart = Yb + NX;         // 32*40 x 64x64 bf16 = 10.5 MB
    float* lpart = (float*)(Opart + (long)32 * NSPLIT_TOT * 4096);

    long n4 = (NX + 4 * NW) / 4;
    cast_all<<<dim3((unsigned)(n4 / 256)), 256, 0, stream>>>(
        x, Wq, Wk, Wv, Wp, xb, wqb, wkb, wvb, wpb);

    gemm_qkv<<<dim3(M_ROWS / 128, C_DIM / 128, 3), 256, 0, stream>>>(
        xb, wqb, wkb, wvb, bq, bk, bv, Qb, Kb, Vtb);

    attn_split<<<dim3(NSPLIT_TOT, B_BATCH * H_HEADS), 256, 0, stream>>>(
        Qb, Kb, Vtb, attn_bias, Opart, lpart);

    attn_combine<<<dim3(T_SEQ / 64, B_BATCH * H_HEADS), 256, 0, stream>>>(
        Opart, lpart, Yb);

    gemm_out_k<<<dim3(M_ROWS / 128, C_DIM / 128), 256, 0, stream>>>(
        Yb, wpb, bp, out);
}

// Round 11
// 126.477 us; speedup vs baseline: 1.1776x; 1.0578x over previous
//
#include <hip/hip_runtime.h>

#define T_SEQ 1024
#define C_DIM 512
#define H_HEADS 8
#define HDIM 64
#define B_BATCH 4
#define M_ROWS (B_BATCH * T_SEQ)   // 4096
#define NSPLIT_TOT 40              // sum over bx of ceil((bx+1)/4)

typedef __attribute__((ext_vector_type(8))) short short8;
typedef __attribute__((ext_vector_type(4))) float f32x4;

__device__ __forceinline__ unsigned short f2bf(float f) {
    unsigned u = __builtin_bit_cast(unsigned, f);
    u += 0x7FFFu + ((u >> 16) & 1u);   // round-to-nearest-even
    return (unsigned short)(u >> 16);
}

__device__ __forceinline__ float bf2f(unsigned short u) {
    return __builtin_bit_cast(float, (unsigned)u << 16);
}

// async global->LDS, 16B per lane; LDS dest = uniform base + lane*16
__device__ __forceinline__ void gload_lds16(const unsigned short* g, unsigned short* l) {
    __builtin_amdgcn_global_load_lds(
        (const __attribute__((address_space(1))) unsigned int*)(const void*)g,
        (__attribute__((address_space(3))) unsigned int*)(void*)l, 16, 0, 0);
}

__device__ __constant__ unsigned char BX_OF[NSPLIT_TOT] =
    {0,1,2,3,4,4,5,5,6,6,7,7,8,8,8,9,9,9,10,10,10,11,11,11,
     12,12,12,12,13,13,13,13,14,14,14,14,15,15,15,15};
__device__ __constant__ unsigned char SP_OF[NSPLIT_TOT] =
    {0,0,0,0,0,1,0,1,0,1,0,1,0,1,2,0,1,2,0,1,2,0,1,2,
     0,1,2,3,0,1,2,3,0,1,2,3,0,1,2,3};
__device__ __constant__ unsigned char CUM_OF[16] =
    {0,1,2,3,4,6,8,10,12,15,18,21,24,28,32,36};

// ---------------------------------------------------------------------------
// Kernel 1: one-shot cast of x + 4 weight matrices to bf16 (r4/r5: fusing the
// cast into GEMM staging costs ~196 MB of per-block fp32 re-reads — never).
// ---------------------------------------------------------------------------
__global__ __launch_bounds__(256) void cast_all(
    const float* __restrict__ x,
    const float* __restrict__ wq, const float* __restrict__ wk,
    const float* __restrict__ wv, const float* __restrict__ wp,
    unsigned short* __restrict__ xb,
    unsigned short* __restrict__ wqb, unsigned short* __restrict__ wkb,
    unsigned short* __restrict__ wvb, unsigned short* __restrict__ wpb)
{
    const long NX = (long)M_ROWS * C_DIM;
    const long NW = (long)C_DIM * C_DIM;
    long i4 = (long)blockIdx.x * blockDim.x + threadIdx.x;
    long base = i4 * 4;
    const float* src; unsigned short* dst; long off;
    if (base < NX) { src = x; dst = xb; off = base; }
    else {
        long r = base - NX;
        int w = (int)(r >> 18);
        off = r & (NW - 1);
        switch (w) {
            case 0:  src = wq; dst = wqb; break;
            case 1:  src = wk; dst = wkb; break;
            case 2:  src = wv; dst = wvb; break;
            default: src = wp; dst = wpb; break;
        }
    }
    float4 v = *(const float4*)(src + off);
    ushort4 o;
    o.x = f2bf(v.x); o.y = f2bf(v.y); o.z = f2bf(v.z); o.w = f2bf(v.w);
    *(ushort4*)(dst + off) = o;
}

// ---------------------------------------------------------------------------
// GEMM, BM=128 x BN=64 tile (occupancy-balanced: qkv 768 blocks = 3/CU exact,
// out 256 blocks = 1/CU exact; the old 128x128 left half the CUs idle on out).
// 256 threads = 4 waves; wave w owns rows [32w,32w+32), all 64 cols; acc[2][4].
// global_load_lds width=16, unpadded LDS, XOR chunk swizzle (r3-proven).
// mode 0: bf16 (B,H,T,HD); mode 1: bf16 (B,H,HD,T) via swapped MFMA operands;
// mode 2: fp32 M x N.
// ---------------------------------------------------------------------------
__device__ __forceinline__ void gemm_body(
    const unsigned short* __restrict__ A,
    const unsigned short* __restrict__ W,
    const float* __restrict__ bias,
    unsigned short* __restrict__ Obf,
    float* __restrict__ Of,
    int mode)
{
    __shared__ __align__(16) unsigned short Atile[128 * 64];
    __shared__ __align__(16) unsigned short Btile[64 * 64];

    const int tid  = threadIdx.x;
    const int w    = tid >> 6;
    const int lane = tid & 63;
    const int quad = lane >> 4;
    const int l16  = lane & 15;
    const int m0   = blockIdx.x * 128;
    const int n0   = blockIdx.y * 64;

    f32x4 acc[2][4] = {};

    const int lr = lane >> 3;
    const int lc = lane & 7;

    for (int k0 = 0; k0 < 512; k0 += 64) {
        __syncthreads();
        // A: wave w rows [32w, 32w+32), 4 issues x 8 rows
        for (int i = 0; i < 4; ++i) {
            int r0 = 32 * w + 8 * i;
            int r  = r0 + lr;
            int c  = lc ^ (r & 7);      // XOR swizzle
            gload_lds16(&A[(long)(m0 + r) * 512 + k0 + c * 8], &Atile[r0 * 64]);
        }
        // B: wave w rows [16w, 16w+16), 2 issues x 8 rows
        for (int i = 0; i < 2; ++i) {
            int r0 = 16 * w + 8 * i;
            int r  = r0 + lr;
            int c  = lc ^ (r & 7);
            gload_lds16(&W[(long)(n0 + r) * 512 + k0 + c * 8], &Btile[r0 * 64]);
        }
        __syncthreads();

        for (int st = 0; st < 2; ++st) {
            const int pc = ((4 * st + quad) ^ (l16 & 7)) * 8;
            short8 af[2], bf[4];
            for (int i = 0; i < 2; ++i)
                af[i] = *(const short8*)&Atile[(32 * w + 16 * i + l16) * 64 + pc];
            for (int j = 0; j < 4; ++j)
                bf[j] = *(const short8*)&Btile[(16 * j + l16) * 64 + pc];
            for (int i = 0; i < 2; ++i)
                for (int j = 0; j < 4; ++j)
                    acc[i][j] = (mode == 1)
                        ? __builtin_amdgcn_mfma_f32_16x16x32_bf16(bf[j], af[i], acc[i][j], 0, 0, 0)
                        : __builtin_amdgcn_mfma_f32_16x16x32_bf16(af[i], bf[j], acc[i][j], 0, 0, 0);
        }
    }

    if (mode == 1) {
        // swapped operands: D rows = W-cols (quad/reg), D cols = tokens (l16)
        for (int j = 0; j < 4; ++j) {
            for (int reg = 0; reg < 4; ++reg) {
                int n = n0 + 16 * j + 4 * quad + reg;
                int h = n >> 6, hd = n & 63;
                float bv = bias[n];
                for (int i = 0; i < 2; ++i) {
                    int t = m0 + 32 * w + 16 * i + l16;
                    int b = t >> 10, tl = t & 1023;
                    Obf[(((long)(b * H_HEADS + h)) * HDIM + hd) * T_SEQ + tl] =
                        f2bf(acc[i][j][reg] + bv);
                }
            }
        }
    } else {
        for (int j = 0; j < 4; ++j) {
            int col = n0 + 16 * j + l16;
            float bv = bias[col];
            for (int i = 0; i < 2; ++i) {
                for (int reg = 0; reg < 4; ++reg) {
                    int row = m0 + 32 * w + 16 * i + 4 * quad + reg;
                    float v = acc[i][j][reg] + bv;
                    if (mode == 2) {
                        Of[(long)row * 512 + col] = v;
                    } else {
                        int b = row >> 10, t = row & 1023;
                        int h = col >> 6,  hd = col & 63;
                        Obf[(((long)(b * H_HEADS + h)) * T_SEQ + t) * HDIM + hd] = f2bf(v);
                    }
                }
            }
        }
    }
}

__global__ __launch_bounds__(256) void gemm_qkv(
    const unsigned short* __restrict__ A,
    const unsigned short* __restrict__ Wq, const unsigned short* __restrict__ Wk,
    const unsigned short* __restrict__ Wv,
    const float* __restrict__ bq, const float* __restrict__ bk, const float* __restrict__ bv,
    unsigned short* __restrict__ Q, unsigned short* __restrict__ K,
    unsigned short* __restrict__ V)
{
    const unsigned short* W; const float* b; unsigned short* O; int mode;
    if (blockIdx.z == 0)      { W = Wq; b = bq; O = Q; mode = 0; }
    else if (blockIdx.z == 1) { W = Wk; b = bk; O = K; mode = 0; }
    else                      { W = Wv; b = bv; O = V; mode = 1; }
    gemm_body(A, W, b, O, nullptr, mode);
}

__global__ __launch_bounds__(256) void gemm_out_k(
    const unsigned short* __restrict__ A, const unsigned short* __restrict__ W,
    const float* __restrict__ bias, float* __restrict__ O)
{
    gemm_body(A, W, bias, nullptr, O, 2);
}

// ---------------------------------------------------------------------------
// Kernel 3a: split-K flash attention (r10, frozen): no-max softmax, slim
// inner loop, async K/V staging, bf16 partials.
// ---------------------------------------------------------------------------
__global__ __launch_bounds__(256) void attn_split(
    const unsigned short* __restrict__ Q, const unsigned short* __restrict__ K,
    const unsigned short* __restrict__ Vt, const float* __restrict__ attn_bias,
    unsigned short* __restrict__ Opart, float* __restrict__ lpart)
{
    __shared__ __align__(16) unsigned short Kl[64 * 64];
    __shared__ __align__(16) unsigned short Vl[64 * 64];     // [hd][key]
    __shared__ __align__(16) unsigned short Pl[4][16 * 72];
    __shared__ float biasl[8][64];

    const int tid  = threadIdx.x;
    const int w    = tid >> 6;
    const int lane = tid & 63;
    const int quad = lane >> 4;
    const int l16  = lane & 15;
    const int lr   = lane >> 3;
    const int lc   = lane & 7;
    const int sidx = blockIdx.x;
    const int bh   = blockIdx.y;
    const int h    = bh & 7;
    const int bx   = BX_OF[sidx];
    const int sp   = SP_OF[sidx];
    const int q0   = bx * 64;
    const int kt0  = sp * 4;
    const int kt1  = min(kt0 + 4, bx + 1);
    const bool use_bias = (q0 < 512) && (sp < 2);   // block-uniform
    const int brow = 2 * w + (quad >> 1);           // bias row, constant per lane
    const int bcol0 = l16 >> 3;                     // + (k0>>3) + 2*ct

    if (use_bias) {
        for (int i = tid; i < 512; i += 256) {
            int nq = (q0 >> 3) + (i >> 6);
            biasl[i >> 6][i & 63] = attn_bias[h * 4096 + nq * 64 + (i & 63)];
        }
    }

    const unsigned short* Qbh = Q  + (long)bh * T_SEQ * HDIM;
    const unsigned short* Kbh = K  + (long)bh * T_SEQ * HDIM;
    const unsigned short* Vbh = Vt + (long)bh * HDIM * T_SEQ;   // [hd][t]

    short8 qf[2];
    {
        int qr = q0 + 16 * w + l16;
        qf[0] = *(const short8*)&Qbh[(long)qr * HDIM + 8 * quad];
        qf[1] = *(const short8*)&Qbh[(long)qr * HDIM + 32 + 8 * quad];
    }

    f32x4 oacc[4] = {};
    float lrow[4] = {0.f, 0.f, 0.f, 0.f};
    const int qrb = q0 + 16 * w + 4 * quad;
    const bool colkeep = (l16 != 15);               // kcol & 15 == l16

    for (int kt = kt0; kt < kt1; ++kt) {
        const int k0 = kt * 64;
        __syncthreads();
        for (int i = 0; i < 2; ++i) {
            int r0 = 16 * w + 8 * i;
            int r  = r0 + lr;
            int c  = lc ^ (r & 7);
            gload_lds16(&Kbh[(long)(k0 + r) * HDIM + c * 8], &Kl[r0 * 64]);
            gload_lds16(&Vbh[(long)r * T_SEQ + k0 + c * 8], &Vl[r0 * 64]);
        }
        __syncthreads();

        // S = Q K^T  (16 x 64 per wave); swizzled fragment reads
        f32x4 s[4] = {};
        for (int st = 0; st < 2; ++st) {
            const int pc = ((4 * st + quad) ^ (l16 & 7)) * 8;
            for (int ct = 0; ct < 4; ++ct) {
                short8 bf = *(const short8*)&Kl[(16 * ct + l16) * 64 + pc];
                s[ct] = __builtin_amdgcn_mfma_f32_16x16x32_bf16(qf[st], bf, s[ct], 0, 0, 0);
            }
        }

        // P = exp(S*scale + bias) with masking; per-lane partial row sums
        const bool diag = (kt == bx);
        for (int ct = 0; ct < 4; ++ct) {
            int kcol = k0 + 16 * ct + l16;
            float bval = use_bias ? biasl[brow][(k0 >> 3) + 2 * ct + bcol0] : 0.f;
            for (int reg = 0; reg < 4; ++reg) {
                float v = s[ct][reg] * 0.125f + bval;
                bool keep = colkeep && (!diag || (kcol <= qrb + reg));
                float p = keep ? __expf(v) : 0.f;
                lrow[reg] += p;
                Pl[w][(4 * quad + reg) * 72 + 16 * ct + l16] = f2bf(p);
            }
        }

        // O += P V; swizzled V fragment reads
        for (int st = 0; st < 2; ++st) {
            const int pc = ((4 * st + quad) ^ (l16 & 7)) * 8;
            short8 af = *(const short8*)&Pl[w][l16 * 72 + 32 * st + 8 * quad];
            for (int ct = 0; ct < 4; ++ct) {
                short8 bf = *(const short8*)&Vl[(16 * ct + l16) * 64 + pc];
                oacc[ct] = __builtin_amdgcn_mfma_f32_16x16x32_bf16(af, bf, oacc[ct], 0, 0, 0);
            }
        }
    }

    // single deferred l-reduction across the 16 lanes of each row group
    for (int off = 1; off < 16; off <<= 1)
        for (int reg = 0; reg < 4; ++reg)
            lrow[reg] += __shfl_xor(lrow[reg], off);

    // partial epilogue (unnormalized, bf16)
    const long p = (long)bh * NSPLIT_TOT + sidx;
    unsigned short* Op = Opart + p * 4096;
    for (int ct = 0; ct < 4; ++ct)
        for (int reg = 0; reg < 4; ++reg)
            Op[(16 * w + 4 * quad + reg) * 64 + 16 * ct + l16] = f2bf(oacc[ct][reg]);
    if (l16 == 0) {
        for (int reg = 0; reg < 4; ++reg) {
            int qr = 16 * w + 4 * quad + reg;
            lpart[p * 64 + qr] = lrow[reg];
        }
    }
}

// ---------------------------------------------------------------------------
// Kernel 3b: combine bf16 splits (plain sum), normalize, write Y bf16 (B,T,C)
// ---------------------------------------------------------------------------
__global__ __launch_bounds__(256) void attn_combine(
    const unsigned short* __restrict__ Opart, const float* __restrict__ lpart,
    unsigned short* __restrict__ Y)
{
    const int bx = blockIdx.x, bh = blockIdx.y;
    const int b = bh >> 3, h = bh & 7;
    const int ns = (bx >> 2) + 1;
    const long p0 = (long)bh * NSPLIT_TOT + CUM_OF[bx];
    const int tid = threadIdx.x;
    const int qr = tid >> 2;
    const int hs = (tid & 3) * 16;

    float L = 0.f;
    for (int s = 0; s < ns; ++s) L += lpart[(p0 + s) * 64 + qr];

    float acc[16] = {};
    for (int s = 0; s < ns; ++s) {
        const unsigned short* op = Opart + (p0 + s) * 4096 + qr * 64 + hs;
        short8 v0 = *(const short8*)op;
        short8 v1 = *(const short8*)(op + 8);
        for (int k = 0; k < 8; ++k) {
            acc[k]     += bf2f((unsigned short)v0[k]);
            acc[k + 8] += bf2f((unsigned short)v1[k]);
        }
    }
    float inv = 1.f / L;
    int q = bx * 64 + qr;
    unsigned short* y = Y + ((long)b * T_SEQ + q) * C_DIM + h * HDIM + hs;
    for (int j4 = 0; j4 < 4; ++j4) {
        ushort4 o;
        o.x = f2bf(acc[4 * j4 + 0] * inv); o.y = f2bf(acc[4 * j4 + 1] * inv);
        o.z = f2bf(acc[4 * j4 + 2] * inv); o.w = f2bf(acc[4 * j4 + 3] * inv);
        *(ushort4*)(y + 4 * j4) = o;
    }
}

// ---------------------------------------------------------------------------
extern "C" void kernel_launch(void* const* d_in, const int* in_sizes, int n_in,
                              void* d_out, int out_size, void* d_ws, size_t ws_size,
                              hipStream_t stream)
{
    const float* x         = (const float*)d_in[0];
    const float* attn_bias = (const float*)d_in[1];
    const float* Wq = (const float*)d_in[2]; const float* bq = (const float*)d_in[3];
    const float* Wk = (const float*)d_in[4]; const float* bk = (const float*)d_in[5];
    const float* Wv = (const float*)d_in[6]; const float* bv = (const float*)d_in[7];
    const float* Wp = (const float*)d_in[8]; const float* bp = (const float*)d_in[9];
    float* out = (float*)d_out;

    const long NX = (long)M_ROWS * C_DIM;    // 2,097,152
    const long NW = (long)C_DIM * C_DIM;     // 262,144

    unsigned short* xb  = (unsigned short*)d_ws;
    unsigned short* wqb = xb  + NX;
    unsigned short* wkb = wqb + NW;
    unsigned short* wvb = wkb + NW;
    unsigned short* wpb = wvb + NW;
    unsigned short* Qb  = wpb + NW;
    unsigned short* Kb  = Qb  + NX;
    unsigned short* Vtb = Kb  + NX;          // transposed (B,H,HD,T)
    unsigned short* Yb  = Vtb + NX;
    unsigned short* Opart = Yb + NX;         // 32*40 x 64x64 bf16 = 10.5 MB
    float* lpart = (float*)(Opart + (long)32 * NSPLIT_TOT * 4096);

    long n4 = (NX + 4 * NW) / 4;
    cast_all<<<dim3((unsigned)(n4 / 256)), 256, 0, stream>>>(
        x, Wq, Wk, Wv, Wp, xb, wqb, wkb, wvb, wpb);

    gemm_qkv<<<dim3(M_ROWS / 128, C_DIM / 64, 3), 256, 0, stream>>>(
        xb, wqb, wkb, wvb, bq, bk, bv, Qb, Kb, Vtb);

    attn_split<<<dim3(NSPLIT_TOT, B_BATCH * H_HEADS), 256, 0, stream>>>(
        Qb, Kb, Vtb, attn_bias, Opart, lpart);

    attn_combine<<<dim3(T_SEQ / 64, B_BATCH * H_HEADS), 256, 0, stream>>>(
        Opart, lpart, Yb);

    gemm_out_k<<<dim3(M_ROWS / 128, C_DIM / 64), 256, 0, stream>>>(
        Yb, wpb, bp, out);
}